// Round 1
// baseline (19666.960 us; speedup 1.0000x reference)
//
#include <hip/hip_runtime.h>
#include <math.h>

#define N 64
#define LDSS 65        // +1 pad: col-pass addresses t*65+p ≡ (t+p) mod 32 -> conflict-free
#define NSWEEPS 8

__global__ __launch_bounds__(64) void logeig_jacobi_kernel(
    const float* __restrict__ Xg, float* __restrict__ out)
{
    __shared__ float Xs[N * LDSS];
    __shared__ float Vs[N * LDSS];
    __shared__ float cs[N / 2];
    __shared__ float ss[N / 2];

    const int t = threadIdx.x;
    const int b = blockIdx.x;
    const float* __restrict__ Xb = Xg + (size_t)b * N * N;

    // ---- load X (coalesced: lane = column), init V = I ----
    for (int i = 0; i < N; ++i) {
        Xs[i * LDSS + t] = Xb[i * N + t];
        Vs[i * LDSS + t] = (i == t) ? 1.0f : 0.0f;
    }
    __syncthreads();

    // ---- cyclic Jacobi, XOR parallel ordering ----
    for (int sweep = 0; sweep < NSWEEPS; ++sweep) {
        for (int m = 1; m < N; ++m) {
            const int hb = 31 - __clz(m);          // highest set bit of m
            const int lowmask = (1 << hb) - 1;

            // 32 rotation angles from pre-round X (threads 0..31)
            if (t < 32) {
                const int k = t;
                const int p = ((k >> hb) << (hb + 1)) | (k & lowmask); // bit hb == 0
                const int q = p ^ m;                                   // bit hb == 1 -> q > p
                const float app = Xs[p * LDSS + p];
                const float aqq = Xs[q * LDSS + q];
                const float apq = Xs[p * LDSS + q];
                float c = 1.0f, s = 0.0f;
                if (fabsf(apq) > 1e-30f) {
                    const float tau = (aqq - app) / (2.0f * apq);
                    float tt = 1.0f / (fabsf(tau) + sqrtf(1.0f + tau * tau));
                    if (tau < 0.0f) tt = -tt;
                    c = rsqrtf(1.0f + tt * tt);
                    s = tt * c;
                }
                cs[k] = c;
                ss[k] = s;
            }
            __syncthreads();

            // row pass: X <- J^T X ; thread owns column j = t
            {
                const int j = t;
                #pragma unroll 8
                for (int k = 0; k < 32; ++k) {
                    const int p = ((k >> hb) << (hb + 1)) | (k & lowmask);
                    const int q = p ^ m;
                    const float c = cs[k], s = ss[k];
                    const float xp = Xs[p * LDSS + j];
                    const float xq = Xs[q * LDSS + j];
                    Xs[p * LDSS + j] = c * xp - s * xq;
                    Xs[q * LDSS + j] = s * xp + c * xq;
                }
            }
            __syncthreads();

            // col pass: X <- X J, V <- V J ; thread owns row i = t
            {
                const int base = t * LDSS;
                #pragma unroll 8
                for (int k = 0; k < 32; ++k) {
                    const int p = ((k >> hb) << (hb + 1)) | (k & lowmask);
                    const int q = p ^ m;
                    const float c = cs[k], s = ss[k];
                    const float xp = Xs[base + p];
                    const float xq = Xs[base + q];
                    Xs[base + p] = c * xp - s * xq;
                    Xs[base + q] = s * xp + c * xq;
                    const float vp = Vs[base + p];
                    const float vq = Vs[base + q];
                    Vs[base + p] = c * vp - s * vq;
                    Vs[base + q] = s * vp + c * vq;
                }
            }
            __syncthreads();
        }
    }

    // ---- logm = V diag(log w) V^T ----
    // thread j holds a[k] = V[j][k] * log(w_k) in registers (fully unrolled)
    float a[N];
    #pragma unroll
    for (int k = 0; k < N; ++k) {
        const float w = Xs[k * LDSS + k];
        const float lw = logf(fmaxf(w, 1e-30f));
        a[k] = Vs[t * LDSS + k] * lw;
    }

    float* __restrict__ outb = out + (size_t)b * N * N;
    for (int i = 0; i < N; ++i) {
        float acc = 0.0f;
        #pragma unroll
        for (int k = 0; k < N; ++k) {
            acc += Vs[i * LDSS + k] * a[k];   // broadcast LDS read (uniform addr)
        }
        outb[i * N + t] = acc;                // coalesced store
    }
}

extern "C" void kernel_launch(void* const* d_in, const int* in_sizes, int n_in,
                              void* d_out, int out_size, void* d_ws, size_t ws_size,
                              hipStream_t stream)
{
    const float* X = (const float*)d_in[0];
    float* out = (float*)d_out;
    const int B = in_sizes[0] / (N * N);   // 8192
    logeig_jacobi_kernel<<<dim3(B), dim3(64), 0, stream>>>(X, out);
}

// Round 3
// 7365.049 us; speedup vs baseline: 2.6703x; 2.6703x over previous
//
#include <hip/hip_runtime.h>
#include <math.h>

#define NSW 8   // fixed sweep count, same budget as the verified R1 kernel

__device__ __forceinline__ float bperm_f(int addr4, float v) {
    return __int_as_float(__builtin_amdgcn_ds_bpermute(addr4, __float_as_int(v)));
}

__global__ __launch_bounds__(64, 2) void logeig_kernel(
    const float* __restrict__ Xg, float* __restrict__ out)
{
    __shared__ float  W[64 * 68];     // staging + reconstruction (68: 16B-aligned rows)
    __shared__ float4 ang[64];        // per-slot (c, s, t, -) — pair-shared EXACT angles
    __shared__ float  lwlds[64];

    const int lane = threadIdx.x;
    const int b = blockIdx.x;

    // ---- stage global -> LDS (coalesced float4) ----
    const float4* __restrict__ Xb4 = (const float4*)(Xg + (size_t)b * 4096);
    for (int j = 0; j < 16; ++j) {
        float4 val = Xb4[j * 64 + lane];
        int f = (j * 64 + lane) * 4;
        int row = f >> 6, col = f & 63;
        *(float4*)&W[row * 68 + col] = val;
    }
    __syncthreads();

    // ---- registers: x = row `lane` of X, v = row `lane` of V, slot-indexed ----
    float x[64], v[64];
    #pragma unroll
    for (int s4 = 0; s4 < 16; ++s4) {
        float4 val = *(const float4*)&W[lane * 68 + s4 * 4];
        x[4 * s4 + 0] = val.x; x[4 * s4 + 1] = val.y;
        x[4 * s4 + 2] = val.z; x[4 * s4 + 3] = val.w;
    }
    #pragma unroll
    for (int s = 0; s < 64; ++s) v[s] = (s == lane) ? 1.f : 0.f;

    float d = W[lane * 68 + lane];    // own diagonal (resynced each sweep)
    int sigma = lane;                 // slot holding row/col `lane`
    int T = lane;                     // lane-as-slot s: row id whose column sits in slot s
    const int tinv4 = ((lane == 0) ? 0 : ((lane == 1) ? 63 : lane - 1)) << 2;

    // ---- cyclic Jacobi, circle-method tournament ordering ----
    for (int sweep = 0; sweep < NSW; ++sweep) {
        for (int t = 0; t < 63; ++t) {
            const int ms = 63 - sigma;                                       // mirror slot
            const int prt4 = __builtin_amdgcn_ds_bpermute(ms << 2, T) << 2;  // partner row id *4
            float aab = 0.f;                                                 // own A[p][q]
            #pragma unroll
            for (int k = 0; k < 64; ++k) aab = (ms == k) ? x[k] : aab;
            const float abb = bperm_f(prt4, d);                              // partner diagonal

            // rotation angle (own perspective; only the lo-side's value gets used)
            const bool ok = fabsf(aab) > 1e-30f;
            const float tau = (abb - d) / (2.f * aab);
            const float at = fabsf(tau);
            const float tt = 1.f / (at + sqrtf(1.f + at * at));
            float tn = (tau >= 0.f) ? tt : -tt;
            float c = rsqrtf(1.f + tn * tn);
            float s = tn * c;
            c = ok ? c : 1.f;  s = ok ? s : 0.f;  tn = ok ? tn : 0.f;

            ang[sigma] = make_float4(c, s, tn, 0.f);
            __syncthreads();

            // Both pair lanes consume the SAME published angle (lo slot), hi side
            // negates s,t -> exact 2-sided congruence, symmetry preserved to ulp.
            const bool lo = (sigma < ms);
            const float4 q = ang[lo ? sigma : ms];
            const float cc = q.x;
            const float ss = lo ? q.y : -q.y;
            const float ts = lo ? q.z : -q.z;
            d = fmaf(-ts, aab, d);                          // Rutishauser diag update

            // row pass: X <- J^T X (full-row exchange with partner via bpermute)
            const float nss = -ss;
            #pragma unroll
            for (int k = 0; k < 64; ++k) {
                const float pk = bperm_f(prt4, x[k]);
                x[k] = fmaf(nss, pk, cc * x[k]);
            }

            // col pass: X <- X J, V <- V J; slot rotation tau folded into writes
            {
                const float4 cs0 = ang[0];
                float xa = x[0], xb = x[63];
                float x_na = fmaf(-cs0.y, xb, cs0.x * xa);
                float x_nb = fmaf( cs0.y, xa, cs0.x * xb);
                float va = v[0], vb = v[63];
                float v_na = fmaf(-cs0.y, vb, cs0.x * va);
                float v_nb = fmaf( cs0.y, va, cs0.x * vb);
                x[0] = x_na; float xsave = x[1]; x[1] = x_nb;
                v[0] = v_na; float vsave = v[1]; v[1] = v_nb;
                #pragma unroll
                for (int r = 1; r < 32; ++r) {
                    const float4 cs = ang[r];
                    const float a  = xsave,  bb = x[63 - r];
                    const float na  = fmaf(-cs.y, bb, cs.x * a);
                    const float nb  = fmaf( cs.y, a,  cs.x * bb);
                    xsave = x[r + 1]; x[r + 1] = na; x[64 - r] = nb;
                    const float av = vsave, bv = v[63 - r];
                    const float nav = fmaf(-cs.y, bv, cs.x * av);
                    const float nbv = fmaf( cs.y, av, cs.x * bv);
                    vsave = v[r + 1]; v[r + 1] = nav; v[64 - r] = nbv;
                }
            }
            __syncthreads();

            sigma = (sigma == 0) ? 0 : ((sigma == 63) ? 1 : sigma + 1);
            T = __builtin_amdgcn_ds_bpermute(tinv4, T);
        }

        // sweep boundary: sigma == lane, T == identity. Resync d to the true
        // (explicitly rotated) diagonal — kills Rutishauser drift.
        float diag = 0.f;
        #pragma unroll
        for (int k = 0; k < 64; ++k) diag = (lane == k) ? x[k] : diag;
        d = diag;
    }

    // ---- reconstruction: out = V diag(log d) V^T  (T == identity here) ----
    lwlds[lane] = logf(fmaxf(d, 1e-30f));
    __syncthreads();

    // W[i][s] = v_i[s] * lw[s]
    #pragma unroll
    for (int s4 = 0; s4 < 16; ++s4) {
        const float4 l4 = *(const float4*)&lwlds[s4 * 4];
        float4 w4;
        w4.x = v[4 * s4 + 0] * l4.x;
        w4.y = v[4 * s4 + 1] * l4.y;
        w4.z = v[4 * s4 + 2] * l4.z;
        w4.w = v[4 * s4 + 3] * l4.w;
        *(float4*)&W[lane * 68 + s4 * 4] = w4;
    }
    __syncthreads();

    // out[i][j] = sum_s W[i][s] * v_j[s]  (uniform b128 reads, coalesced stores)
    float* __restrict__ outb = out + (size_t)b * 4096;
    for (int i = 0; i < 64; ++i) {
        float acc = 0.f;
        #pragma unroll
        for (int s4 = 0; s4 < 16; ++s4) {
            const float4 w4 = *(const float4*)&W[i * 68 + s4 * 4];
            acc = fmaf(w4.x, v[4 * s4 + 0], acc);
            acc = fmaf(w4.y, v[4 * s4 + 1], acc);
            acc = fmaf(w4.z, v[4 * s4 + 2], acc);
            acc = fmaf(w4.w, v[4 * s4 + 3], acc);
        }
        outb[i * 64 + lane] = acc;
    }
}

extern "C" void kernel_launch(void* const* d_in, const int* in_sizes, int n_in,
                              void* d_out, int out_size, void* d_ws, size_t ws_size,
                              hipStream_t stream)
{
    const float* X = (const float*)d_in[0];
    float* out = (float*)d_out;
    const int B = in_sizes[0] / 4096;   // 8192 matrices of 64x64
    logeig_kernel<<<dim3(B), dim3(64), 0, stream>>>(X, out);
}